// Round 1
// 395.780 us; speedup vs baseline: 1.0652x; 1.0652x over previous
//
#include <hip/hip_runtime.h>

#define N_GRAPHS    8
#define EDGES_PER_G 2048
#define NN          8192
#define EE          16384
#define IN_DIM      10
#define EDGE_DIM    9
#define HID         64
#define OUT_DIM     3
#define TT          5
#define EPSN        1e-6f

typedef float f32x4 __attribute__((ext_vector_type(4)));
typedef short bf16x8s __attribute__((ext_vector_type(8)));

union BF8 { __bf16 h[8]; bf16x8s v; };

// ------- edge MLP, wave-per-4-edges (lane = channel), transposed h2T output ------
// h2T[c*EE+e] = relu(relu(norm(ear[e]) @ w1 + b1) @ w2 + b2)[c]
// sh/st are [4][HID] LDS staging; no per-thread arrays (avoid scratch spill).
__device__ inline void edgemlp_body_T(int e0, int tid,
    const float* __restrict__ ear, const float* __restrict__ meanb,
    const float* __restrict__ invstd,
    const float* __restrict__ w1, const float* __restrict__ b1,
    const float* __restrict__ w2, const float* __restrict__ b2,
    float (*sh)[HID], float (*st)[HID], float* __restrict__ h2T) {
  int g = tid >> 6, lane = tid & 63;
  int e = e0 + g;
  int gg = e >> 11;                        // 2048 edges per graph
  const float* er = ear + (size_t)e * EDGE_DIM;
  const float* mb = meanb + gg * EDGE_DIM;
  const float* is = invstd + gg * EDGE_DIM;
  float xn[EDGE_DIM];
#pragma unroll
  for (int d = 0; d < EDGE_DIM; ++d) xn[d] = (er[d] - mb[d]) * is[d];
  float a = b1[lane];
#pragma unroll
  for (int d = 0; d < EDGE_DIM; ++d) a += xn[d] * w1[d * HID + lane];
  sh[g][lane] = fmaxf(a, 0.f);
  __syncthreads();
  float o = b2[lane];
#pragma unroll
  for (int h = 0; h < HID; ++h) o += sh[g][h] * w2[h * HID + lane];
  st[g][lane] = fmaxf(o, 0.f);
  __syncthreads();
  // transposed write: thread t -> channel c = t>>2, edge offset eo = t&3
  int c = tid >> 2, eo = tid & 3;
  h2T[(size_t)c * EE + e0 + eo] = st[eo][c];
}

// ---------------- preamble: lift | bprep(permuted) | deg | stats | zero-aggr ------
__global__ __launch_bounds__(256) void k_pre(
    const float* __restrict__ x,
    const float* __restrict__ lw1, const float* __restrict__ lb1,
    const float* __restrict__ lw2, const float* __restrict__ lb2,
    float* __restrict__ v,
    const float* __restrict__ kw3, const float* __restrict__ kb3,
    unsigned short* __restrict__ Bbf,
    const int* __restrict__ dst, float* __restrict__ degf,
    const float* __restrict__ ear, float* __restrict__ meanb,
    float* __restrict__ invstd, float* __restrict__ aggr) {
  __shared__ float sh[4][HID];
  int b = blockIdx.x;
  int g = threadIdx.x >> 6, lane = threadIdx.x & 63;
  if (b < NN / 4) {
    // ---- lift MLP ----
    int n = b * 4 + g;
    const float* xr = x + n * IN_DIM;
    float a = lb1[lane];
#pragma unroll
    for (int d = 0; d < IN_DIM; ++d) a += xr[d] * lw1[d * HID + lane];
    sh[g][lane] = fmaxf(a, 0.f);
    __syncthreads();
    float o = lb2[lane];
#pragma unroll
    for (int h = 0; h < HID; ++h) o += sh[g][h] * lw2[h * HID + lane];
    v[n * HID + lane] = o;
  } else if (b < NN / 4 + 1024) {
    // ---- bprep: kw3 (+kb3 as row 64) -> bf16, FRAGMENT-MAJOR layout:
    //      Bbf[t][c][(s*4+nt)*512 + lane*8 + jj], element = W3[c][nt*16+n15][s*32+q*8+jj]
    const int total = TT * 65 * 4096;
    for (int i = (b - NN / 4) * 256 + (int)threadIdx.x; i < total; i += 1024 * 256) {
      int xx   = i & 4095;
      int call = i >> 12;
      int t = call / 65;
      int c = call - t * 65;
      int sn = xx >> 9;              // s*4+nt
      int s  = sn >> 2, nt = sn & 3;
      int l9 = xx & 511;
      int ln = l9 >> 3, jj = l9 & 7;
      int nn15 = ln & 15, qq = ln >> 4;
      int x_in = (nt * 16 + nn15) * 64 + s * 32 + qq * 8 + jj;
      float val = (c < 64) ? kw3[(size_t)(t * 64 + c) * 4096 + x_in]
                           : kb3[(size_t)t * 4096 + x_in];
      union { __bf16 h; unsigned short s16; } u;
      u.h = (__bf16)val;
      Bbf[i] = u.s16;
    }
  } else if (b < NN / 4 + 1024 + EE / 256) {
    // ---- deg histogram ----
    int e = (b - (NN / 4 + 1024)) * 256 + threadIdx.x;
    atomicAdd(&degf[dst[e]], 1.f);
  } else if (b < NN / 4 + 1024 + EE / 256 + N_GRAPHS) {
    // ---- per-graph edge_attr stats: per-thread accumulate, wave shuffle-reduce,
    //      per-wave partials in LDS, 9 threads finalize. (Old version did
    //      18 same-address LDS atomicAdds x 256 threads = 4.6K serialized RMWs
    //      per block -> the 47us straggler tail.)
    int gg = b - (NN / 4 + 1024 + EE / 256);
    float ls[EDGE_DIM], lq[EDGE_DIM];
#pragma unroll
    for (int d = 0; d < EDGE_DIM; ++d) { ls[d] = 0.f; lq[d] = 0.f; }
    for (int e = threadIdx.x; e < EDGES_PER_G; e += blockDim.x) {
      const float* row = ear + (size_t)(gg * EDGES_PER_G + e) * EDGE_DIM;
#pragma unroll
      for (int d = 0; d < EDGE_DIM; ++d) { float xv = row[d]; ls[d] += xv; lq[d] += xv * xv; }
    }
#pragma unroll
    for (int d = 0; d < EDGE_DIM; ++d) {
#pragma unroll
      for (int off = 32; off > 0; off >>= 1) {
        ls[d] += __shfl_down(ls[d], off);
        lq[d] += __shfl_down(lq[d], off);
      }
    }
    if (lane == 0) {
#pragma unroll
      for (int d = 0; d < EDGE_DIM; ++d) {
        sh[g][d] = ls[d];
        sh[g][EDGE_DIM + d] = lq[d];
      }
    }
    __syncthreads();
    if (threadIdx.x < EDGE_DIM) {
      int d = threadIdx.x;
      float s0 = sh[0][d] + sh[1][d] + sh[2][d] + sh[3][d];
      float q0 = sh[0][EDGE_DIM + d] + sh[1][EDGE_DIM + d] +
                 sh[2][EDGE_DIM + d] + sh[3][EDGE_DIM + d];
      float m  = s0 * (1.0f / EDGES_PER_G);
      float mq = q0 * (1.0f / EDGES_PER_G);
      float var = fmaxf(mq - m * m, 0.f);
      meanb[gg * EDGE_DIM + d]  = m;
      invstd[gg * EDGE_DIM + d] = 1.f / (sqrtf(var) + EPSN);
    }
  } else {
    // ---- zero aggr (float4, 512 blocks) ----
    int idx = (b - (NN / 4 + 1024 + EE / 256 + N_GRAPHS)) * 256 + threadIdx.x;
    ((float4*)aggr)[idx] = make_float4(0.f, 0.f, 0.f, 0.f);
  }
}

// ---------------- standalone edge MLP (layer 0), EE/4 blocks ----------------
__global__ __launch_bounds__(256) void k_em(const float* __restrict__ ear,
    const float* __restrict__ meanb, const float* __restrict__ invstd,
    const float* __restrict__ w1, const float* __restrict__ b1,
    const float* __restrict__ w2, const float* __restrict__ b2,
    float* __restrict__ h2T) {
  __shared__ float sh[4][HID];
  __shared__ float st[4][HID];
  edgemlp_body_T(blockIdx.x * 4, threadIdx.x, ear, meanb, invstd,
                 w1, b1, w2, b2, sh, st, h2T);
}

// ---------------- msg GEMM: Msg[E,64] = A[E,4160] @ B[4160,64], scatter by dst ----
// h-folded form: A-fragment = bf16(v[src]) built ONCE per wave (constant across
// channels); per channel c: tmp = u @ W3_c via MFMA (C=0 chain over s), then
// acc += h2[e,c] * tmp in fp32 VALU (h loaded as float4 over C/D rows q*4..+3).
// Halves per-cc VALU (was 32 mul + 32 cvt building bf16(h*v) every channel)
// and keeps h at full fp32 precision. B layout fragment-major as before.
__global__ __launch_bounds__(256) void k_msg(const float* __restrict__ v,
    const float* __restrict__ h2T, const unsigned short* __restrict__ Bt,
    const int* __restrict__ src, const int* __restrict__ dst,
    float* __restrict__ aggr) {
  int kchunk = blockIdx.x & 3;
  int ebb    = (blockIdx.x >> 2) * 128;
  int w    = threadIdx.x >> 6;
  int lane = threadIdx.x & 63;
  int n15  = lane & 15;
  int q    = lane >> 4;
  int ebase = ebb + w * 32;

  // load v rows, convert to bf16 A-fragments once
  bf16x8s ubf[2][2];   // [m-tile][k-step s]
#pragma unroll
  for (int mt = 0; mt < 2; ++mt) {
    int e = ebase + mt * 16 + n15;
    const float4* vr = (const float4*)(v + (size_t)src[e] * HID);
    int f0 = q * 2;
#pragma unroll
    for (int s = 0; s < 2; ++s) {
      float4 pa = vr[s * 8 + f0], pb = vr[s * 8 + f0 + 1];
      BF8 u;
      u.h[0] = (__bf16)pa.x; u.h[1] = (__bf16)pa.y;
      u.h[2] = (__bf16)pa.z; u.h[3] = (__bf16)pa.w;
      u.h[4] = (__bf16)pb.x; u.h[5] = (__bf16)pb.y;
      u.h[6] = (__bf16)pb.z; u.h[7] = (__bf16)pb.w;
      ubf[mt][s] = u.v;
    }
  }

  f32x4 acc[2][4];
#pragma unroll
  for (int mt = 0; mt < 2; ++mt)
#pragma unroll
    for (int nt = 0; nt < 4; ++nt) acc[mt][nt] = (f32x4)0.0f;

  int c0 = kchunk * 16;
  const unsigned short* Bp = Bt + (size_t)c0 * 4096 + lane * 8;
  const float* hq = h2T + (size_t)c0 * EE + ebase + q * 4;

#pragma unroll 4
  for (int cc = 0; cc < 16; ++cc) {
    const unsigned short* Bc = Bp + (size_t)cc * 4096;
    bf16x8s bfr[2][4];
#pragma unroll
    for (int s = 0; s < 2; ++s)
#pragma unroll
      for (int nt = 0; nt < 4; ++nt)
        bfr[s][nt] = *(const bf16x8s*)(Bc + (s * 4 + nt) * 512);
    float4 h4[2];
    h4[0] = *(const float4*)(hq + (size_t)cc * EE);
    h4[1] = *(const float4*)(hq + (size_t)cc * EE + 16);
    f32x4 tmp[2][4];
#pragma unroll
    for (int mt = 0; mt < 2; ++mt)
#pragma unroll
      for (int nt = 0; nt < 4; ++nt) {
        f32x4 t0 = __builtin_amdgcn_mfma_f32_16x16x32_bf16(
            ubf[mt][0], bfr[0][nt], (f32x4)0.0f, 0, 0, 0);
        tmp[mt][nt] = __builtin_amdgcn_mfma_f32_16x16x32_bf16(
            ubf[mt][1], bfr[1][nt], t0, 0, 0, 0);
      }
#pragma unroll
    for (int mt = 0; mt < 2; ++mt) {
      float4 hh = h4[mt];
#pragma unroll
      for (int nt = 0; nt < 4; ++nt) {
        acc[mt][nt][0] += hh.x * tmp[mt][nt][0];
        acc[mt][nt][1] += hh.y * tmp[mt][nt][1];
        acc[mt][nt][2] += hh.z * tmp[mt][nt][2];
        acc[mt][nt][3] += hh.w * tmp[mt][nt][3];
      }
    }
  }

  if (kchunk == 3) {
    // bias row c = 64 (h == 1): accumulate directly, A-fragment is ubf
    const unsigned short* Bc = Bt + (size_t)64 * 4096 + lane * 8;
    bf16x8s bfr[2][4];
#pragma unroll
    for (int s = 0; s < 2; ++s)
#pragma unroll
      for (int nt = 0; nt < 4; ++nt)
        bfr[s][nt] = *(const bf16x8s*)(Bc + (s * 4 + nt) * 512);
#pragma unroll
    for (int s = 0; s < 2; ++s)
#pragma unroll
      for (int mt = 0; mt < 2; ++mt)
#pragma unroll
        for (int nt = 0; nt < 4; ++nt)
          acc[mt][nt] = __builtin_amdgcn_mfma_f32_16x16x32_bf16(
              ubf[mt][s], bfr[s][nt], acc[mt][nt], 0, 0, 0);
  }

  // epilogue: C/D row = q*4+r (edge), col = n15; scatter-add by dst
#pragma unroll
  for (int mt = 0; mt < 2; ++mt) {
#pragma unroll
    for (int r = 0; r < 4; ++r) {
      int e = ebase + mt * 16 + q * 4 + r;
      int d = dst[e];
      float* ag = aggr + (size_t)d * HID;
#pragma unroll
      for (int nt = 0; nt < 4; ++nt)
        atomicAdd(ag + nt * 16 + n15, acc[mt][nt][r]);
    }
  }
}

// ------- update(t) [blocks 0..2047] + edge MLP for t+1 [blocks 2048..6143] -------
__global__ __launch_bounds__(256) void k_upd_em(
    float* __restrict__ v, const float* __restrict__ rw, const float* __restrict__ rb,
    float* __restrict__ aggr, const float* __restrict__ degf,
    const float* __restrict__ ear, const float* __restrict__ meanb,
    const float* __restrict__ invstd,
    const float* __restrict__ w1, const float* __restrict__ b1,
    const float* __restrict__ w2, const float* __restrict__ b2,
    float* __restrict__ h2T) {
  __shared__ float sh[4][HID];
  __shared__ float st[4][HID];
  int g = threadIdx.x >> 6, lane = threadIdx.x & 63;
  if (blockIdx.x < NN / 4) {
    int n = blockIdx.x * 4 + g;
    int idx = n * HID + lane;
    sh[g][lane] = v[idx];
    __syncthreads();
    float inv = 1.f / fmaxf(degf[n], 1.f);
    float o = rb[lane] + aggr[idx] * inv;
    aggr[idx] = 0.f;                       // re-zero for next layer
#pragma unroll
    for (int h = 0; h < HID; ++h) o += sh[g][h] * rw[h * HID + lane];
    v[idx] = fmaxf(o, 0.f);
  } else {
    int e0 = (blockIdx.x - NN / 4) * 4;
    edgemlp_body_T(e0, threadIdx.x, ear, meanb, invstd,
                   w1, b1, w2, b2, sh, st, h2T);
  }
}

// ------- final layer: update(T-1) + proj fused (per-node elementwise) ------------
__global__ __launch_bounds__(256) void k_upd_proj(
    const float* __restrict__ v, const float* __restrict__ rw,
    const float* __restrict__ rb,
    const float* __restrict__ aggr, const float* __restrict__ degf,
    const float* __restrict__ pw1, const float* __restrict__ pb1,
    const float* __restrict__ pw2, const float* __restrict__ pb2,
    float* __restrict__ out) {
  __shared__ float sh[4][HID];
  int g = threadIdx.x >> 6, lane = threadIdx.x & 63;
  int n = blockIdx.x * 4 + g;
  int idx = n * HID + lane;
  sh[g][lane] = v[idx];
  __syncthreads();
  float inv = 1.f / fmaxf(degf[n], 1.f);
  float o = rb[lane] + aggr[idx] * inv;
#pragma unroll
  for (int h = 0; h < HID; ++h) o += sh[g][h] * rw[h * HID + lane];
  float vn = fmaxf(o, 0.f);
  __syncthreads();
  sh[g][lane] = vn;                       // updated v row
  __syncthreads();
  float a = pb1[lane];
#pragma unroll
  for (int h = 0; h < HID; ++h) a += sh[g][h] * pw1[h * HID + lane];
  float h1 = fmaxf(a, 0.f);
  __syncthreads();
  sh[g][lane] = h1;
  __syncthreads();
  if (lane < OUT_DIM) {
    float oo = pb2[lane];
#pragma unroll
    for (int h = 0; h < HID; ++h) oo += sh[g][h] * pw2[h * OUT_DIM + lane];
    out[n * OUT_DIM + lane] = oo;
  }
}

extern "C" void kernel_launch(void* const* d_in, const int* in_sizes, int n_in,
                              void* d_out, int out_size, void* d_ws, size_t ws_size,
                              hipStream_t stream) {
  const float* x        = (const float*)d_in[0];
  const float* ear      = (const float*)d_in[1];
  const float* lift_w1  = (const float*)d_in[2];
  const float* lift_b1  = (const float*)d_in[3];
  const float* lift_w2  = (const float*)d_in[4];
  const float* lift_b2  = (const float*)d_in[5];
  const float* root_w   = (const float*)d_in[6];
  const float* root_b   = (const float*)d_in[7];
  const float* kw1      = (const float*)d_in[8];
  const float* kb1      = (const float*)d_in[9];
  const float* kw2      = (const float*)d_in[10];
  const float* kb2      = (const float*)d_in[11];
  const float* kw3      = (const float*)d_in[12];
  const float* kb3      = (const float*)d_in[13];
  const float* pw1      = (const float*)d_in[14];
  const float* pb1      = (const float*)d_in[15];
  const float* pw2      = (const float*)d_in[16];
  const float* pb2      = (const float*)d_in[17];
  const int* edge_index = (const int*)d_in[18];
  const int* src = edge_index;
  const int* dst = edge_index + EE;
  float* out = (float*)d_out;

  float* ws     = (float*)d_ws;
  float* aggr   = ws;                          // NN*HID
  float* degf   = aggr + NN * HID;             // NN
  float* h2T    = degf + NN;                   // HID*EE (transposed)
  float* vbuf   = h2T + (size_t)HID * EE;      // NN*HID
  float* meanb  = vbuf + NN * HID;             // 72
  float* invstd = meanb + 72;                  // 72
  unsigned short* Bbf = (unsigned short*)(invstd + 72);  // TT*65*4096 bf16

  hipMemsetAsync(degf, 0, NN * sizeof(float), stream);
  const int PRE_BLOCKS = NN / 4 + 1024 + EE / 256 + N_GRAPHS + NN * HID / 1024;
  k_pre<<<PRE_BLOCKS, 256, 0, stream>>>(
      x, lift_w1, lift_b1, lift_w2, lift_b2, vbuf, kw3, kb3, Bbf,
      dst, degf, ear, meanb, invstd, aggr);
  k_em<<<EE / 4, 256, 0, stream>>>(ear, meanb, invstd,
      kw1, kb1, kw2, kb2, h2T);

  for (int t = 0; t < TT; ++t) {
    k_msg<<<512, 256, 0, stream>>>(vbuf, h2T, Bbf + (size_t)t * 65 * 4096,
                                   src, dst, aggr);
    if (t < TT - 1) {
      int tt = t + 1;
      k_upd_em<<<NN / 4 + EE / 4, 256, 0, stream>>>(
          vbuf, root_w + (size_t)t * HID * HID, root_b + (size_t)t * HID,
          aggr, degf, ear, meanb, invstd,
          kw1 + (size_t)tt * EDGE_DIM * HID, kb1 + (size_t)tt * HID,
          kw2 + (size_t)tt * HID * HID, kb2 + (size_t)tt * HID, h2T);
    } else {
      k_upd_proj<<<NN / 4, 256, 0, stream>>>(
          vbuf, root_w + (size_t)t * HID * HID, root_b + (size_t)t * HID,
          aggr, degf, pw1, pb1, pw2, pb2, out);
    }
  }
}

// Round 2
// 366.466 us; speedup vs baseline: 1.1504x; 1.0800x over previous
//
#include <hip/hip_runtime.h>

#define N_GRAPHS    8
#define EDGES_PER_G 2048
#define NN          8192
#define EE          16384
#define IN_DIM      10
#define EDGE_DIM    9
#define HID         64
#define OUT_DIM     3
#define TT          5
#define EPSN        1e-6f

typedef float f32x4 __attribute__((ext_vector_type(4)));
typedef short bf16x8s __attribute__((ext_vector_type(8)));

union BF8 { __bf16 h[8]; bf16x8s v; };

// ------- edge MLP, wave-per-4-edges (lane = channel), transposed h2T output ------
// h2T[c*EE+e] = relu(relu(norm(ear[e]) @ w1 + b1) @ w2 + b2)[c]
__device__ inline void edgemlp_body_T(int e0, int tid,
    const float* __restrict__ ear, const float* __restrict__ meanb,
    const float* __restrict__ invstd,
    const float* __restrict__ w1, const float* __restrict__ b1,
    const float* __restrict__ w2, const float* __restrict__ b2,
    float (*sh)[HID], float (*st)[HID], float* __restrict__ h2T) {
  int g = tid >> 6, lane = tid & 63;
  int e = e0 + g;
  int gg = e >> 11;                        // 2048 edges per graph
  const float* er = ear + (size_t)e * EDGE_DIM;
  const float* mb = meanb + gg * EDGE_DIM;
  const float* is = invstd + gg * EDGE_DIM;
  float xn[EDGE_DIM];
#pragma unroll
  for (int d = 0; d < EDGE_DIM; ++d) xn[d] = (er[d] - mb[d]) * is[d];
  float a = b1[lane];
#pragma unroll
  for (int d = 0; d < EDGE_DIM; ++d) a += xn[d] * w1[d * HID + lane];
  sh[g][lane] = fmaxf(a, 0.f);
  __syncthreads();
  float o = b2[lane];
#pragma unroll
  for (int h = 0; h < HID; ++h) o += sh[g][h] * w2[h * HID + lane];
  st[g][lane] = fmaxf(o, 0.f);
  __syncthreads();
  // transposed write: thread t -> channel c = t>>2, edge offset eo = t&3
  int c = tid >> 2, eo = tid & 3;
  h2T[(size_t)c * EE + e0 + eo] = st[eo][c];
}

// ---------------- k_stats: per-graph edge stats (8 blocks) + zero degf (8) -------
__global__ __launch_bounds__(256) void k_stats(
    const float* __restrict__ ear, float* __restrict__ meanb,
    float* __restrict__ invstd, float* __restrict__ degf) {
  __shared__ float sw[4][2 * EDGE_DIM];
  int b = blockIdx.x;
  int g = threadIdx.x >> 6, lane = threadIdx.x & 63;
  if (b < N_GRAPHS) {
    int gg = b;
    float ls[EDGE_DIM], lq[EDGE_DIM];
#pragma unroll
    for (int d = 0; d < EDGE_DIM; ++d) { ls[d] = 0.f; lq[d] = 0.f; }
    for (int e = threadIdx.x; e < EDGES_PER_G; e += blockDim.x) {
      const float* row = ear + (size_t)(gg * EDGES_PER_G + e) * EDGE_DIM;
#pragma unroll
      for (int d = 0; d < EDGE_DIM; ++d) { float xv = row[d]; ls[d] += xv; lq[d] += xv * xv; }
    }
#pragma unroll
    for (int d = 0; d < EDGE_DIM; ++d) {
#pragma unroll
      for (int off = 32; off > 0; off >>= 1) {
        ls[d] += __shfl_down(ls[d], off);
        lq[d] += __shfl_down(lq[d], off);
      }
    }
    if (lane == 0) {
#pragma unroll
      for (int d = 0; d < EDGE_DIM; ++d) {
        sw[g][d] = ls[d];
        sw[g][EDGE_DIM + d] = lq[d];
      }
    }
    __syncthreads();
    if (threadIdx.x < EDGE_DIM) {
      int d = threadIdx.x;
      float s0 = sw[0][d] + sw[1][d] + sw[2][d] + sw[3][d];
      float q0 = sw[0][EDGE_DIM + d] + sw[1][EDGE_DIM + d] +
                 sw[2][EDGE_DIM + d] + sw[3][EDGE_DIM + d];
      float m  = s0 * (1.0f / EDGES_PER_G);
      float mq = q0 * (1.0f / EDGES_PER_G);
      float var = fmaxf(mq - m * m, 0.f);
      meanb[gg * EDGE_DIM + d]  = m;
      invstd[gg * EDGE_DIM + d] = 1.f / (sqrtf(var) + EPSN);
    }
  } else {
    // zero degf: 8 blocks x 256 threads x float4 = 8192 floats
    int idx = (b - N_GRAPHS) * 256 + threadIdx.x;
    ((float4*)degf)[idx] = make_float4(0.f, 0.f, 0.f, 0.f);
  }
}

// -------- k_pre: em(layer0) | lift | bprep | deg-hist | zero-aggr ----------------
__global__ __launch_bounds__(256) void k_pre(
    const float* __restrict__ x,
    const float* __restrict__ lw1, const float* __restrict__ lb1,
    const float* __restrict__ lw2, const float* __restrict__ lb2,
    float* __restrict__ v,
    const float* __restrict__ kw3, const float* __restrict__ kb3,
    unsigned short* __restrict__ Bbf,
    const int* __restrict__ dst, float* __restrict__ degf,
    const float* __restrict__ ear, const float* __restrict__ meanb,
    const float* __restrict__ invstd, float* __restrict__ aggr,
    const float* __restrict__ w1, const float* __restrict__ b1,
    const float* __restrict__ w2, const float* __restrict__ b2,
    float* __restrict__ h2T0) {
  __shared__ float sh[4][HID];
  __shared__ float st[4][HID];
  int b = blockIdx.x;
  int g = threadIdx.x >> 6, lane = threadIdx.x & 63;
  if (b < EE / 4) {
    // ---- edge MLP for layer 0 (4096 blocks, launched first = longest pole) ----
    edgemlp_body_T(b * 4, threadIdx.x, ear, meanb, invstd, w1, b1, w2, b2,
                   sh, st, h2T0);
  } else if (b < EE / 4 + NN / 4) {
    // ---- lift MLP ----
    int n = (b - EE / 4) * 4 + g;
    const float* xr = x + n * IN_DIM;
    float a = lb1[lane];
#pragma unroll
    for (int d = 0; d < IN_DIM; ++d) a += xr[d] * lw1[d * HID + lane];
    sh[g][lane] = fmaxf(a, 0.f);
    __syncthreads();
    float o = lb2[lane];
#pragma unroll
    for (int h = 0; h < HID; ++h) o += sh[g][h] * lw2[h * HID + lane];
    v[n * HID + lane] = o;
  } else if (b < EE / 4 + NN / 4 + 1024) {
    // ---- bprep: kw3 (+kb3 as row 64) -> bf16 fragment-major ----
    const int total = TT * 65 * 4096;
    for (int i = (b - (EE / 4 + NN / 4)) * 256 + (int)threadIdx.x; i < total;
         i += 1024 * 256) {
      int xx   = i & 4095;
      int call = i >> 12;
      int t = call / 65;
      int c = call - t * 65;
      int sn = xx >> 9;              // s*4+nt
      int s  = sn >> 2, nt = sn & 3;
      int l9 = xx & 511;
      int ln = l9 >> 3, jj = l9 & 7;
      int nn15 = ln & 15, qq = ln >> 4;
      int x_in = (nt * 16 + nn15) * 64 + s * 32 + qq * 8 + jj;
      float val = (c < 64) ? kw3[(size_t)(t * 64 + c) * 4096 + x_in]
                           : kb3[(size_t)t * 4096 + x_in];
      union { __bf16 h; unsigned short s16; } u;
      u.h = (__bf16)val;
      Bbf[i] = u.s16;
    }
  } else if (b < EE / 4 + NN / 4 + 1024 + EE / 256) {
    // ---- deg histogram (degf zeroed in k_stats) ----
    int e = (b - (EE / 4 + NN / 4 + 1024)) * 256 + threadIdx.x;
    atomicAdd(&degf[dst[e]], 1.f);
  } else {
    // ---- zero aggr (float4, 512 blocks) ----
    int idx = (b - (EE / 4 + NN / 4 + 1024 + EE / 256)) * 256 + threadIdx.x;
    ((float4*)aggr)[idx] = make_float4(0.f, 0.f, 0.f, 0.f);
  }
}

// ---------------- msg GEMM + overlapped edge MLP for next layer ------------------
// Blocks 0..511: 32 edges each, ALL 65 channels (wave w -> channels w*16..+15,
// wave 3 also bias row 64). Partials LDS-reduced across waves -> ONE atomic pass
// (was 4 kchunk blocks x full-width atomics = 4x the RMW traffic).
// Blocks 512..512+nEm: edge MLP for layer t+1 into h2T_w (overlaps with MFMA).
__global__ __launch_bounds__(256) void k_msg(const float* __restrict__ v,
    const float* __restrict__ h2T_r, const unsigned short* __restrict__ Bt,
    const int* __restrict__ src, const int* __restrict__ dst,
    float* __restrict__ aggr, int nEm,
    const float* __restrict__ ear, const float* __restrict__ meanb,
    const float* __restrict__ invstd,
    const float* __restrict__ w1, const float* __restrict__ b1,
    const float* __restrict__ w2, const float* __restrict__ b2,
    float* __restrict__ h2T_w) {
  __shared__ float red[4][32][68];          // 34.8 KB; +68 pad vs bank conflicts
  int b = blockIdx.x;
  if (b < 512) {
    int w    = threadIdx.x >> 6;
    int lane = threadIdx.x & 63;
    int n15  = lane & 15;
    int q    = lane >> 4;
    int ebase = b * 32;

    // load v rows for 32 edges, convert to bf16 A-fragments once
    bf16x8s ubf[2][2];   // [m-tile][k-step s]
#pragma unroll
    for (int mt = 0; mt < 2; ++mt) {
      int e = ebase + mt * 16 + n15;
      const float4* vr = (const float4*)(v + (size_t)src[e] * HID);
      int f0 = q * 2;
#pragma unroll
      for (int s = 0; s < 2; ++s) {
        float4 pa = vr[s * 8 + f0], pb = vr[s * 8 + f0 + 1];
        BF8 u;
        u.h[0] = (__bf16)pa.x; u.h[1] = (__bf16)pa.y;
        u.h[2] = (__bf16)pa.z; u.h[3] = (__bf16)pa.w;
        u.h[4] = (__bf16)pb.x; u.h[5] = (__bf16)pb.y;
        u.h[6] = (__bf16)pb.z; u.h[7] = (__bf16)pb.w;
        ubf[mt][s] = u.v;
      }
    }

    f32x4 acc[2][4];
#pragma unroll
    for (int mt = 0; mt < 2; ++mt)
#pragma unroll
      for (int nt = 0; nt < 4; ++nt) acc[mt][nt] = (f32x4)0.0f;

    int c0 = w * 16;
    const unsigned short* Bp = Bt + (size_t)c0 * 4096 + lane * 8;
    const float* hq = h2T_r + (size_t)c0 * EE + ebase + q * 4;

#pragma unroll 4
    for (int cc = 0; cc < 16; ++cc) {
      const unsigned short* Bc = Bp + (size_t)cc * 4096;
      bf16x8s bfr[2][4];
#pragma unroll
      for (int s = 0; s < 2; ++s)
#pragma unroll
        for (int nt = 0; nt < 4; ++nt)
          bfr[s][nt] = *(const bf16x8s*)(Bc + (s * 4 + nt) * 512);
      float4 h4[2];
      h4[0] = *(const float4*)(hq + (size_t)cc * EE);
      h4[1] = *(const float4*)(hq + (size_t)cc * EE + 16);
      f32x4 tmp[2][4];
#pragma unroll
      for (int mt = 0; mt < 2; ++mt)
#pragma unroll
        for (int nt = 0; nt < 4; ++nt) {
          f32x4 t0 = __builtin_amdgcn_mfma_f32_16x16x32_bf16(
              ubf[mt][0], bfr[0][nt], (f32x4)0.0f, 0, 0, 0);
          tmp[mt][nt] = __builtin_amdgcn_mfma_f32_16x16x32_bf16(
              ubf[mt][1], bfr[1][nt], t0, 0, 0, 0);
        }
#pragma unroll
      for (int mt = 0; mt < 2; ++mt) {
        float4 hh = h4[mt];
#pragma unroll
        for (int nt = 0; nt < 4; ++nt) {
          acc[mt][nt][0] += hh.x * tmp[mt][nt][0];
          acc[mt][nt][1] += hh.y * tmp[mt][nt][1];
          acc[mt][nt][2] += hh.z * tmp[mt][nt][2];
          acc[mt][nt][3] += hh.w * tmp[mt][nt][3];
        }
      }
    }

    if (w == 3) {
      // bias row c = 64 (h == 1): accumulate directly, A-fragment is ubf
      const unsigned short* Bc = Bt + (size_t)64 * 4096 + lane * 8;
      bf16x8s bfr[2][4];
#pragma unroll
      for (int s = 0; s < 2; ++s)
#pragma unroll
        for (int nt = 0; nt < 4; ++nt)
          bfr[s][nt] = *(const bf16x8s*)(Bc + (s * 4 + nt) * 512);
#pragma unroll
      for (int s = 0; s < 2; ++s)
#pragma unroll
        for (int mt = 0; mt < 2; ++mt)
#pragma unroll
          for (int nt = 0; nt < 4; ++nt)
            acc[mt][nt] = __builtin_amdgcn_mfma_f32_16x16x32_bf16(
                ubf[mt][s], bfr[s][nt], acc[mt][nt], 0, 0, 0);
    }

    // stage partials: C/D row = q*4+r (edge in tile), col = nt*16+n15
#pragma unroll
    for (int mt = 0; mt < 2; ++mt)
#pragma unroll
      for (int nt = 0; nt < 4; ++nt)
#pragma unroll
        for (int r = 0; r < 4; ++r)
          red[w][mt * 16 + q * 4 + r][nt * 16 + n15] = acc[mt][nt][r];
    __syncthreads();

    // cross-wave reduce + single atomic pass (8 outputs per thread)
    for (int i = threadIdx.x; i < 32 * HID; i += 256) {
      int e = i >> 6, c = i & 63;
      float s = red[0][e][c] + red[1][e][c] + red[2][e][c] + red[3][e][c];
      atomicAdd(aggr + (size_t)dst[ebase + e] * HID + c, s);
    }
  } else if (b < 512 + nEm) {
    // ---- edge MLP for NEXT layer, overlapped with MFMA blocks ----
    float (*sh)[HID] = (float (*)[HID])&red[0][0][0];
    float (*st)[HID] = (float (*)[HID])(&red[0][0][0] + 4 * HID);
    edgemlp_body_T((b - 512) * 4, threadIdx.x, ear, meanb, invstd,
                   w1, b1, w2, b2, sh, st, h2T_w);
  }
}

// ------- pure update(t) (edge MLP moved into k_msg) ------------------------------
__global__ __launch_bounds__(256) void k_upd(
    float* __restrict__ v, const float* __restrict__ rw, const float* __restrict__ rb,
    float* __restrict__ aggr, const float* __restrict__ degf) {
  __shared__ float sh[4][HID];
  int g = threadIdx.x >> 6, lane = threadIdx.x & 63;
  int n = blockIdx.x * 4 + g;
  int idx = n * HID + lane;
  sh[g][lane] = v[idx];
  __syncthreads();
  float inv = 1.f / fmaxf(degf[n], 1.f);
  float o = rb[lane] + aggr[idx] * inv;
  aggr[idx] = 0.f;                       // re-zero for next layer
#pragma unroll
  for (int h = 0; h < HID; ++h) o += sh[g][h] * rw[h * HID + lane];
  v[idx] = fmaxf(o, 0.f);
}

// ------- final layer: update(T-1) + proj fused (per-node elementwise) ------------
__global__ __launch_bounds__(256) void k_upd_proj(
    const float* __restrict__ v, const float* __restrict__ rw,
    const float* __restrict__ rb,
    const float* __restrict__ aggr, const float* __restrict__ degf,
    const float* __restrict__ pw1, const float* __restrict__ pb1,
    const float* __restrict__ pw2, const float* __restrict__ pb2,
    float* __restrict__ out) {
  __shared__ float sh[4][HID];
  int g = threadIdx.x >> 6, lane = threadIdx.x & 63;
  int n = blockIdx.x * 4 + g;
  int idx = n * HID + lane;
  sh[g][lane] = v[idx];
  __syncthreads();
  float inv = 1.f / fmaxf(degf[n], 1.f);
  float o = rb[lane] + aggr[idx] * inv;
#pragma unroll
  for (int h = 0; h < HID; ++h) o += sh[g][h] * rw[h * HID + lane];
  float vn = fmaxf(o, 0.f);
  __syncthreads();
  sh[g][lane] = vn;                       // updated v row
  __syncthreads();
  float a = pb1[lane];
#pragma unroll
  for (int h = 0; h < HID; ++h) a += sh[g][h] * pw1[h * HID + lane];
  float h1 = fmaxf(a, 0.f);
  __syncthreads();
  sh[g][lane] = h1;
  __syncthreads();
  if (lane < OUT_DIM) {
    float oo = pb2[lane];
#pragma unroll
    for (int h = 0; h < HID; ++h) oo += sh[g][h] * pw2[h * OUT_DIM + lane];
    out[n * OUT_DIM + lane] = oo;
  }
}

extern "C" void kernel_launch(void* const* d_in, const int* in_sizes, int n_in,
                              void* d_out, int out_size, void* d_ws, size_t ws_size,
                              hipStream_t stream) {
  const float* x        = (const float*)d_in[0];
  const float* ear      = (const float*)d_in[1];
  const float* lift_w1  = (const float*)d_in[2];
  const float* lift_b1  = (const float*)d_in[3];
  const float* lift_w2  = (const float*)d_in[4];
  const float* lift_b2  = (const float*)d_in[5];
  const float* root_w   = (const float*)d_in[6];
  const float* root_b   = (const float*)d_in[7];
  const float* kw1      = (const float*)d_in[8];
  const float* kb1      = (const float*)d_in[9];
  const float* kw2      = (const float*)d_in[10];
  const float* kb2      = (const float*)d_in[11];
  const float* kw3      = (const float*)d_in[12];
  const float* kb3      = (const float*)d_in[13];
  const float* pw1      = (const float*)d_in[14];
  const float* pb1      = (const float*)d_in[15];
  const float* pw2      = (const float*)d_in[16];
  const float* pb2      = (const float*)d_in[17];
  const int* edge_index = (const int*)d_in[18];
  const int* src = edge_index;
  const int* dst = edge_index + EE;
  float* out = (float*)d_out;

  float* ws     = (float*)d_ws;
  float* aggr   = ws;                          // NN*HID
  float* degf   = aggr + NN * HID;             // NN
  float* h2Ta   = degf + NN;                   // HID*EE (transposed, buf A)
  float* h2Tb   = h2Ta + (size_t)HID * EE;     // HID*EE (buf B)
  float* vbuf   = h2Tb + (size_t)HID * EE;     // NN*HID
  float* meanb  = vbuf + NN * HID;             // 72
  float* invstd = meanb + 72;                  // 72
  unsigned short* Bbf = (unsigned short*)(invstd + 72);  // TT*65*4096 bf16

  k_stats<<<2 * N_GRAPHS, 256, 0, stream>>>(ear, meanb, invstd, degf);

  const int PRE_BLOCKS = EE / 4 + NN / 4 + 1024 + EE / 256 + NN * HID / 1024;
  k_pre<<<PRE_BLOCKS, 256, 0, stream>>>(
      x, lift_w1, lift_b1, lift_w2, lift_b2, vbuf, kw3, kb3, Bbf,
      dst, degf, ear, meanb, invstd, aggr,
      kw1, kb1, kw2, kb2, h2Ta);

  for (int t = 0; t < TT; ++t) {
    const float* hr = (t & 1) ? h2Tb : h2Ta;
    float*       hw = (t & 1) ? h2Ta : h2Tb;
    int nEm = (t < TT - 1) ? EE / 4 : 0;
    int tt  = (t < TT - 1) ? t + 1 : t;    // em weights for next layer
    k_msg<<<512 + nEm, 256, 0, stream>>>(
        vbuf, hr, Bbf + (size_t)t * 65 * 4096, src, dst, aggr, nEm,
        ear, meanb, invstd,
        kw1 + (size_t)tt * EDGE_DIM * HID, kb1 + (size_t)tt * HID,
        kw2 + (size_t)tt * HID * HID, kb2 + (size_t)tt * HID, hw);
    if (t < TT - 1) {
      k_upd<<<NN / 4, 256, 0, stream>>>(
          vbuf, root_w + (size_t)t * HID * HID, root_b + (size_t)t * HID,
          aggr, degf);
    } else {
      k_upd_proj<<<NN / 4, 256, 0, stream>>>(
          vbuf, root_w + (size_t)t * HID * HID, root_b + (size_t)t * HID,
          aggr, degf, pw1, pb1, pw2, pb2, out);
    }
  }
}